// Round 1
// baseline (982.645 us; speedup 1.0000x reference)
//
#include <hip/hip_runtime.h>

#define N_NODES 20000
#define N_EDGES 640000

typedef short short8 __attribute__((ext_vector_type(8)));
typedef float f32x4 __attribute__((ext_vector_type(4)));

// RNE float -> bf16 bits
__device__ __forceinline__ unsigned short f2bf(float x){
  unsigned int u = __builtin_bit_cast(unsigned int, x);
  u += 0x7fffu + ((u >> 16) & 1u);
  return (unsigned short)(u >> 16);
}

// ---------------- y = per-irrep linear (l1) ----------------
__global__ void k_y(const float* __restrict__ ni, const float* __restrict__ na,
                    const float* __restrict__ Wl10, const float* __restrict__ Wl11,
                    float* __restrict__ y){
  int gid = blockIdx.x*256 + threadIdx.x;
  if (gid >= N_NODES*80) return;
  int n = gid / 80, k = gid - n*80;
  const float* row = ni + (size_t)n*80;
  float a = na[n];
  float acc = 0.f;
  if (k < 32){
    #pragma unroll
    for (int u=0; u<32; ++u) acc += row[u]*Wl10[u*32+k];
    y[gid] = acc * a * 0.17677669529663687f;  // 1/sqrt(32)
  } else {
    int kk = k-32, v = kk/3, i = kk - v*3;
    #pragma unroll
    for (int u=0; u<16; ++u) acc += row[32+u*3+i]*Wl11[u*16+v];
    y[gid] = acc * a * 0.25f;                  // 1/sqrt(16)
  }
}

// ---------------- CSR build ----------------
__global__ void k_hist(const int* __restrict__ ei, int* __restrict__ counts){
  int e = blockIdx.x*256 + threadIdx.x;
  if (e < N_EDGES) atomicAdd(&counts[ei[N_EDGES + e]], 1);
}

__global__ void k_scan(const int* __restrict__ counts, int* __restrict__ cursor){
  __shared__ int wsum[16];
  __shared__ int s_run;
  int t = threadIdx.x;            // 1024 threads
  int lane = t & 63, wv = t >> 6;
  if (t == 0) s_run = 0;
  __syncthreads();
  for (int base = 0; base < N_NODES; base += 1024){
    int i = base + t;
    int v = (i < N_NODES) ? counts[i] : 0;
    int x = v;
    #pragma unroll
    for (int off=1; off<64; off<<=1){
      int sh = __shfl_up(x, off, 64);
      if (lane >= off) x += sh;
    }
    if (lane == 63) wsum[wv] = x;
    __syncthreads();
    if (wv == 0 && lane < 16){
      int s = wsum[lane];
      #pragma unroll
      for (int off=1; off<16; off<<=1){
        int sh = __shfl_up(s, off, 64);
        if (lane >= off) s += sh;
      }
      wsum[lane] = s;
    }
    __syncthreads();
    int wbase = (wv == 0) ? 0 : wsum[wv-1];
    int run = s_run;
    if (i < N_NODES) cursor[i] = run + wbase + (x - v);
    __syncthreads();
    if (t == 0) s_run = run + wsum[15];
    __syncthreads();
  }
}

__global__ void k_fill(const int* __restrict__ ei, int* __restrict__ cursor, int* __restrict__ eid){
  int e = blockIdx.x*256 + threadIdx.x;
  if (e < N_EDGES){
    int pos = atomicAdd(&cursor[ei[N_EDGES + e]], 1);
    eid[pos] = e;
  }
}

// ---------------- fused edge MLP + messages + segment-sum ----------------
// 64 dst-sorted edges per block of 256 threads.
__global__ __launch_bounds__(256) void k_edge(
    const float* __restrict__ edge_attr, const float* __restrict__ edge_scalars,
    const float* __restrict__ Wfc0, const float* __restrict__ Wfc1,
    const int* __restrict__ ei, const int* __restrict__ eid_sorted,
    const float* __restrict__ y, float* __restrict__ agg){
  __shared__ float s_wfc0[640];                          // [k=10][n=64] f32
  __shared__ __align__(16) unsigned short s_wfc1t[96*72];// [o=96][j=64(+8 pad)] bf16
  __shared__ float s_es[64*10];
  __shared__ __align__(16) unsigned short s_h[64*72];    // [e=64][j=64(+8 pad)] bf16
  __shared__ float s_w[64*97];                           // [e=64][o=96(+1 pad)] f32
  __shared__ float s_ea[64*4];
  __shared__ int s_src[64], s_dst[64], s_eid[64];

  int t = threadIdx.x;
  int b = blockIdx.x;

  if (t < 64){
    int ev = eid_sorted[b*64 + t];
    s_eid[t] = ev;
    s_src[t] = ei[ev];
    s_dst[t] = ei[N_EDGES + ev];
    *(float4*)(s_ea + t*4) = *(const float4*)(edge_attr + (size_t)ev*4);
  }
  for (int idx = t; idx < 640; idx += 256) s_wfc0[idx] = Wfc0[idx];
  for (int idx = t; idx < 6144; idx += 256){
    int j = idx / 96, o = idx - j*96;
    s_wfc1t[o*72 + j] = f2bf(Wfc1[idx]);
  }
  __syncthreads();
  for (int idx = t; idx < 640; idx += 256){
    int e = idx / 10, k = idx - e*10;
    s_es[idx] = edge_scalars[(size_t)s_eid[e]*10 + k];
  }
  __syncthreads();

  // ---- layer1: h = silu(es @ Wfc0 / sqrt(10)) -> bf16 in LDS
  {
    int e = t >> 2, q = t & 3;
    const float* esr = s_es + e*10;
    float hv[16];
    #pragma unroll
    for (int n2=0; n2<16; ++n2) hv[n2] = 0.f;
    #pragma unroll
    for (int k=0; k<10; ++k){
      float evv = esr[k];
      const float* wr = s_wfc0 + k*64 + q*16;
      #pragma unroll
      for (int n2=0; n2<16; ++n2) hv[n2] += evv * wr[n2];
    }
    unsigned int pk[8];
    #pragma unroll
    for (int n2=0; n2<8; ++n2){
      float x0v = hv[2*n2]   * 0.31622776601683794f;
      float x1v = hv[2*n2+1] * 0.31622776601683794f;
      float h0 = x0v / (1.f + __expf(-x0v));
      float h1 = x1v / (1.f + __expf(-x1v));
      pk[n2] = (unsigned int)f2bf(h0) | ((unsigned int)f2bf(h1) << 16);
    }
    uint4* dp = (uint4*)(s_h + e*72 + q*16);
    dp[0] = make_uint4(pk[0],pk[1],pk[2],pk[3]);
    dp[1] = make_uint4(pk[4],pk[5],pk[6],pk[7]);
  }
  __syncthreads();

  // ---- layer2: w = h @ Wfc1 / 8 via MFMA 16x16x32 bf16 (K=64 in 2 steps)
  {
    int wv = t >> 6, lane = t & 63;
    int row = lane & 15, kg = lane >> 4;
    int m_base = wv*16;
    const short8 a0 = *(const short8*)(s_h + (m_base+row)*72 + kg*8);
    const short8 a1 = *(const short8*)(s_h + (m_base+row)*72 + 32 + kg*8);
    #pragma unroll
    for (int nt=0; nt<6; ++nt){
      int n = nt*16 + row;
      const short8 b0 = *(const short8*)(s_wfc1t + n*72 + kg*8);
      const short8 b1 = *(const short8*)(s_wfc1t + n*72 + 32 + kg*8);
      f32x4 acc = {0.f,0.f,0.f,0.f};
      acc = __builtin_amdgcn_mfma_f32_16x16x32_bf16(a0, b0, acc, 0, 0, 0);
      acc = __builtin_amdgcn_mfma_f32_16x16x32_bf16(a1, b1, acc, 0, 0, 0);
      #pragma unroll
      for (int r=0; r<4; ++r)
        s_w[(m_base + kg*4 + r)*97 + nt*16 + row] = acc[r] * 0.125f;  // /sqrt(64)
    }
  }
  __syncthreads();

  // ---- messages + per-block segment sum over sorted dst, one channel per lane
  if (t < 192){
    int c = t;
    int mode, o, yoff, fi = 0;
    if (c < 32)      { mode=0; o=c;    yoff=c; }
    else if (c < 48) { int u=c-32;  mode=1; o=80+u; yoff=32+3*u; }
    else if (c < 144){ int idx=c-48;  int u=idx/3; fi=idx-u*3; mode=2; o=32+u; yoff=u; }
    else             { int idx=c-144; int u=idx/3; int i=idx-u*3; mode=3; o=64+u; yoff=32+3*u+i; }
    float acc = 0.f;
    for (int e=0; e<64; ++e){
      const float* yr = y + (size_t)s_src[e]*80;
      float wv = s_w[e*97 + o];
      const float* ea = s_ea + e*4;
      float m;
      if (mode == 0)      m = wv * yr[yoff] * ea[0];
      else if (mode == 1) m = wv * (yr[yoff]*ea[1] + yr[yoff+1]*ea[2] + yr[yoff+2]*ea[3]) * 0.5773502691896258f;
      else if (mode == 2) m = wv * yr[yoff] * ea[1+fi];
      else                m = wv * yr[yoff] * ea[0];
      acc += m;
      int dcur = s_dst[e];
      int dnext = (e == 63) ? -1 : s_dst[e+1];
      if (dnext != dcur){
        unsafeAtomicAdd(&agg[(size_t)dcur*192 + c], acc);
        acc = 0.f;
      }
    }
  }
}

// ---------------- finish: z = agg @ W_l2, out = c_s*s + c_x*z ----------------
__global__ void k_finish(const float* __restrict__ ni, const float* __restrict__ na,
    const float* __restrict__ Wsc0, const float* __restrict__ Wsc1,
    const float* __restrict__ Wl20, const float* __restrict__ Wl21,
    const float* __restrict__ agg, float* __restrict__ out){
  int gid = blockIdx.x*256 + threadIdx.x;
  if (gid >= N_NODES*80) return;
  int n = gid / 80, k = gid - n*80;
  const float* row = ni + (size_t)n*80;
  const float* ag  = agg + (size_t)n*192;
  float a = na[n];
  const float c_s = 0.3826834323650898f;   // sin(pi/8)
  const float c_x = 0.9238795325112867f;   // cos(pi/8)
  const float zscale = 0.17677669529663687f * 0.14433756729740643f; // 1/sqrt(32)/sqrt(48)
  float s = 0.f, z = 0.f;
  if (k < 32){
    #pragma unroll
    for (int u=0; u<32; ++u) s += row[u]*Wsc0[u*32+k];
    s *= a * 0.17677669529663687f;
    #pragma unroll
    for (int u=0; u<48; ++u) z += ag[u]*Wl20[u*32+k];
  } else {
    int kk=k-32, v=kk/3, i=kk-v*3;
    #pragma unroll
    for (int u=0; u<16; ++u) s += row[32+u*3+i]*Wsc1[u*16+v];
    s *= a * 0.25f;
    #pragma unroll
    for (int u=0; u<48; ++u) z += ag[48+u*3+i]*Wl21[u*16+v];
  }
  out[gid] = c_s*s + c_x*z*zscale;
}

extern "C" void kernel_launch(void* const* d_in, const int* in_sizes, int n_in,
                              void* d_out, int out_size, void* d_ws, size_t ws_size,
                              hipStream_t stream){
  const float* node_input   = (const float*)d_in[0];
  const float* node_attr    = (const float*)d_in[1];
  const float* edge_attr    = (const float*)d_in[2];
  const float* edge_scalars = (const float*)d_in[3];
  const float* W_sc0 = (const float*)d_in[4];
  const float* W_sc1 = (const float*)d_in[5];
  const float* W_l1_0 = (const float*)d_in[6];
  const float* W_l1_1 = (const float*)d_in[7];
  const float* W_fc0 = (const float*)d_in[8];
  const float* W_fc1 = (const float*)d_in[9];
  const float* W_l2_0 = (const float*)d_in[10];
  const float* W_l2_1 = (const float*)d_in[11];
  const int* edge_index = (const int*)d_in[12];
  float* out = (float*)d_out;

  char* ws = (char*)d_ws;
  float* y    = (float*)ws;                                // 6,400,000 B
  float* agg  = (float*)(ws + 6400000);                    // 15,360,000 B
  int* counts = (int*)(ws + 6400000 + 15360000);           // 80,000 B
  int* cursor = counts + 20000;                            // 80,000 B
  int* eids   = cursor + 20000;                            // 2,560,000 B

  hipMemsetAsync(agg, 0, (size_t)N_NODES*192*sizeof(float), stream);
  hipMemsetAsync(counts, 0, (size_t)N_NODES*sizeof(int), stream);

  k_y   <<<(N_NODES*80+255)/256, 256, 0, stream>>>(node_input, node_attr, W_l1_0, W_l1_1, y);
  k_hist<<<(N_EDGES+255)/256, 256, 0, stream>>>(edge_index, counts);
  k_scan<<<1, 1024, 0, stream>>>(counts, cursor);
  k_fill<<<(N_EDGES+255)/256, 256, 0, stream>>>(edge_index, cursor, eids);
  k_edge<<<N_EDGES/64, 256, 0, stream>>>(edge_attr, edge_scalars, W_fc0, W_fc1,
                                         edge_index, eids, y, agg);
  k_finish<<<(N_NODES*80+255)/256, 256, 0, stream>>>(node_input, node_attr, W_sc0, W_sc1,
                                                     W_l2_0, W_l2_1, agg, out);
}

// Round 2
// 591.990 us; speedup vs baseline: 1.6599x; 1.6599x over previous
//
#include <hip/hip_runtime.h>

#define N_NODES 20000
#define N_EDGES 640000
#define N_TILES (N_EDGES/64)

typedef short short8 __attribute__((ext_vector_type(8)));
typedef float f32x4 __attribute__((ext_vector_type(4)));

// RNE float -> bf16 bits
__device__ __forceinline__ unsigned short f2bf(float x){
  unsigned int u = __builtin_bit_cast(unsigned int, x);
  u += 0x7fffu + ((u >> 16) & 1u);
  return (unsigned short)(u >> 16);
}

// ---------------- y = per-irrep linear (l1) ----------------
__global__ void k_y(const float* __restrict__ ni, const float* __restrict__ na,
                    const float* __restrict__ Wl10, const float* __restrict__ Wl11,
                    float* __restrict__ y){
  int gid = blockIdx.x*256 + threadIdx.x;
  if (gid >= N_NODES*80) return;
  int n = gid / 80, k = gid - n*80;
  const float* row = ni + (size_t)n*80;
  float a = na[n];
  float acc = 0.f;
  if (k < 32){
    #pragma unroll
    for (int u=0; u<32; ++u) acc += row[u]*Wl10[u*32+k];
    y[gid] = acc * a * 0.17677669529663687f;  // 1/sqrt(32)
  } else {
    int kk = k-32, v = kk/3, i = kk - v*3;
    #pragma unroll
    for (int u=0; u<16; ++u) acc += row[32+u*3+i]*Wl11[u*16+v];
    y[gid] = acc * a * 0.25f;                  // 1/sqrt(16)
  }
}

// ---------------- CSR build ----------------
__global__ void k_hist(const int* __restrict__ ei, int* __restrict__ counts){
  int e = blockIdx.x*256 + threadIdx.x;
  if (e < N_EDGES) atomicAdd(&counts[ei[N_EDGES + e]], 1);
}

__global__ void k_scan(const int* __restrict__ counts, int* __restrict__ cursor){
  __shared__ int wsum[16];
  __shared__ int s_run;
  int t = threadIdx.x;            // 1024 threads
  int lane = t & 63, wv = t >> 6;
  if (t == 0) s_run = 0;
  __syncthreads();
  for (int base = 0; base < N_NODES; base += 1024){
    int i = base + t;
    int v = (i < N_NODES) ? counts[i] : 0;
    int x = v;
    #pragma unroll
    for (int off=1; off<64; off<<=1){
      int sh = __shfl_up(x, off, 64);
      if (lane >= off) x += sh;
    }
    if (lane == 63) wsum[wv] = x;
    __syncthreads();
    if (wv == 0 && lane < 16){
      int s = wsum[lane];
      #pragma unroll
      for (int off=1; off<16; off<<=1){
        int sh = __shfl_up(s, off, 64);
        if (lane >= off) s += sh;
      }
      wsum[lane] = s;
    }
    __syncthreads();
    int wbase = (wv == 0) ? 0 : wsum[wv-1];
    int run = s_run;
    if (i < N_NODES) cursor[i] = run + wbase + (x - v);
    __syncthreads();
    if (t == 0) s_run = run + wsum[15];
    __syncthreads();
  }
}

__global__ void k_fill(const int* __restrict__ ei, int* __restrict__ cursor, int* __restrict__ eid){
  int e = blockIdx.x*256 + threadIdx.x;
  if (e < N_EDGES){
    int pos = atomicAdd(&cursor[ei[N_EDGES + e]], 1);
    eid[pos] = e;
  }
}

// ---------------- fused edge MLP + messages + segment-sum ----------------
// Persistent blocks: weights staged ONCE, then loop over 64-edge tiles.
__global__ __launch_bounds__(256) void k_edge(
    const float* __restrict__ edge_attr, const float* __restrict__ edge_scalars,
    const float* __restrict__ Wfc0, const float* __restrict__ Wfc1,
    const int* __restrict__ ei, const int* __restrict__ eid_sorted,
    const float* __restrict__ y, float* __restrict__ agg){
  __shared__ float s_wfc0[640];                          // [k=10][n=64] f32
  __shared__ __align__(16) unsigned short s_wfc1t[96*72];// [o=96][j=64(+8 pad)] bf16
  __shared__ float s_es[64*10];
  __shared__ __align__(16) unsigned short s_h[64*72];    // [e=64][j=64(+8 pad)] bf16
  __shared__ float s_w[64*97];                           // [e=64][o=96(+1 pad)] f32
  __shared__ float s_y[64*80];                           // [e=64][k=80] f32 gathered y rows
  __shared__ float s_ea[64*4];
  __shared__ int s_src[64], s_dst[64], s_eid[64];

  int t = threadIdx.x;

  // ---- one-time weight staging
  for (int idx = t; idx < 640; idx += 256) s_wfc0[idx] = Wfc0[idx];
  for (int idx = t; idx < 6144; idx += 256){
    int j = idx / 96, o = idx - j*96;
    s_wfc1t[o*72 + j] = f2bf(Wfc1[idx]);
  }

  // ---- per-lane message-channel constants (modes 0,2,3 unified)
  int o_c=0, yoff=0, eaidx=0;
  bool isdot = false;
  if (t < 192){
    int c = t;
    if (c < 32)      { o_c=c;            yoff=c;            eaidx=0; }
    else if (c < 48) { int u=c-32;       o_c=80+u;          yoff=32+3*u; isdot=true; }
    else if (c < 144){ int idx=c-48;  int u=idx/3; int fi=idx-u*3; o_c=32+u;  yoff=u;        eaidx=1+fi; }
    else             { int idx=c-144; int u=idx/3; int i =idx-u*3; o_c=64+u;  yoff=32+3*u+i; eaidx=0; }
  }

  for (int tile = blockIdx.x; tile < N_TILES; tile += gridDim.x){
    if (t < 64){
      int ev = eid_sorted[tile*64 + t];
      s_eid[t] = ev;
      s_src[t] = ei[ev];
      s_dst[t] = ei[N_EDGES + ev];
      *(float4*)(s_ea + t*4) = *(const float4*)(edge_attr + (size_t)ev*4);
    }
    __syncthreads();
    // stage edge scalars + gather y rows into LDS (coalesced)
    for (int idx = t; idx < 640; idx += 256){
      int e = idx / 10, k = idx - e*10;
      s_es[idx] = edge_scalars[(size_t)s_eid[e]*10 + k];
    }
    for (int idx = t; idx < 1280; idx += 256){
      int e = idx / 20, q = idx - e*20;
      *(float4*)(s_y + e*80 + q*4) = *(const float4*)(y + (size_t)s_src[e]*80 + q*4);
    }
    __syncthreads();

    // ---- layer1: h = silu(es @ Wfc0 / sqrt(10)) -> bf16 in LDS
    {
      int e = t >> 2, q = t & 3;
      const float* esr = s_es + e*10;
      float hv[16];
      #pragma unroll
      for (int n2=0; n2<16; ++n2) hv[n2] = 0.f;
      #pragma unroll
      for (int k=0; k<10; ++k){
        float evv = esr[k];
        const float* wr = s_wfc0 + k*64 + q*16;
        #pragma unroll
        for (int n2=0; n2<16; ++n2) hv[n2] += evv * wr[n2];
      }
      unsigned int pk[8];
      #pragma unroll
      for (int n2=0; n2<8; ++n2){
        float x0v = hv[2*n2]   * 0.31622776601683794f;
        float x1v = hv[2*n2+1] * 0.31622776601683794f;
        float h0 = x0v / (1.f + __expf(-x0v));
        float h1 = x1v / (1.f + __expf(-x1v));
        pk[n2] = (unsigned int)f2bf(h0) | ((unsigned int)f2bf(h1) << 16);
      }
      uint4* dp = (uint4*)(s_h + e*72 + q*16);
      dp[0] = make_uint4(pk[0],pk[1],pk[2],pk[3]);
      dp[1] = make_uint4(pk[4],pk[5],pk[6],pk[7]);
    }
    __syncthreads();

    // ---- layer2: w = h @ Wfc1 / 8 via MFMA 16x16x32 bf16 (K=64 in 2 steps)
    {
      int wv = t >> 6, lane = t & 63;
      int row = lane & 15, kg = lane >> 4;
      int m_base = wv*16;
      const short8 a0 = *(const short8*)(s_h + (m_base+row)*72 + kg*8);
      const short8 a1 = *(const short8*)(s_h + (m_base+row)*72 + 32 + kg*8);
      #pragma unroll
      for (int nt=0; nt<6; ++nt){
        int n = nt*16 + row;
        const short8 b0 = *(const short8*)(s_wfc1t + n*72 + kg*8);
        const short8 b1 = *(const short8*)(s_wfc1t + n*72 + 32 + kg*8);
        f32x4 acc = {0.f,0.f,0.f,0.f};
        acc = __builtin_amdgcn_mfma_f32_16x16x32_bf16(a0, b0, acc, 0, 0, 0);
        acc = __builtin_amdgcn_mfma_f32_16x16x32_bf16(a1, b1, acc, 0, 0, 0);
        #pragma unroll
        for (int r=0; r<4; ++r)
          s_w[(m_base + kg*4 + r)*97 + nt*16 + row] = acc[r] * 0.125f;  // /sqrt(64)
      }
    }
    __syncthreads();

    // ---- messages + per-block segment sum over sorted dst, one channel/lane
    if (t < 192){
      float acc = 0.f;
      int dcur = s_dst[0];
      #pragma unroll 4
      for (int e=0; e<64; ++e){
        float wv = s_w[e*97 + o_c];
        float m;
        if (isdot){
          const float* yr = s_y + e*80 + yoff;
          const float* ea = s_ea + e*4;
          m = wv * (yr[0]*ea[1] + yr[1]*ea[2] + yr[2]*ea[3]) * 0.5773502691896258f;
        } else {
          m = wv * s_y[e*80 + yoff] * s_ea[e*4 + eaidx];
        }
        acc += m;
        int dnext = (e == 63) ? -1 : s_dst[e+1];
        if (dnext != dcur){
          unsafeAtomicAdd(&agg[(size_t)dcur*192 + t], acc);
          acc = 0.f;
        }
        dcur = dnext;
      }
    }
    __syncthreads();
  }
}

// ---------------- finish: z = agg @ W_l2, out = c_s*s + c_x*z ----------------
__global__ void k_finish(const float* __restrict__ ni, const float* __restrict__ na,
    const float* __restrict__ Wsc0, const float* __restrict__ Wsc1,
    const float* __restrict__ Wl20, const float* __restrict__ Wl21,
    const float* __restrict__ agg, float* __restrict__ out){
  int gid = blockIdx.x*256 + threadIdx.x;
  if (gid >= N_NODES*80) return;
  int n = gid / 80, k = gid - n*80;
  const float* row = ni + (size_t)n*80;
  const float* ag  = agg + (size_t)n*192;
  float a = na[n];
  const float c_s = 0.3826834323650898f;   // sin(pi/8)
  const float c_x = 0.9238795325112867f;   // cos(pi/8)
  const float zscale = 0.17677669529663687f * 0.14433756729740643f; // 1/sqrt(32)/sqrt(48)
  float s = 0.f, z = 0.f;
  if (k < 32){
    #pragma unroll
    for (int u=0; u<32; ++u) s += row[u]*Wsc0[u*32+k];
    s *= a * 0.17677669529663687f;
    #pragma unroll
    for (int u=0; u<48; ++u) z += ag[u]*Wl20[u*32+k];
  } else {
    int kk=k-32, v=kk/3, i=kk-v*3;
    #pragma unroll
    for (int u=0; u<16; ++u) s += row[32+u*3+i]*Wsc1[u*16+v];
    s *= a * 0.25f;
    #pragma unroll
    for (int u=0; u<48; ++u) z += ag[48+u*3+i]*Wl21[u*16+v];
  }
  out[gid] = c_s*s + c_x*z*zscale;
}

extern "C" void kernel_launch(void* const* d_in, const int* in_sizes, int n_in,
                              void* d_out, int out_size, void* d_ws, size_t ws_size,
                              hipStream_t stream){
  const float* node_input   = (const float*)d_in[0];
  const float* node_attr    = (const float*)d_in[1];
  const float* edge_attr    = (const float*)d_in[2];
  const float* edge_scalars = (const float*)d_in[3];
  const float* W_sc0 = (const float*)d_in[4];
  const float* W_sc1 = (const float*)d_in[5];
  const float* W_l1_0 = (const float*)d_in[6];
  const float* W_l1_1 = (const float*)d_in[7];
  const float* W_fc0 = (const float*)d_in[8];
  const float* W_fc1 = (const float*)d_in[9];
  const float* W_l2_0 = (const float*)d_in[10];
  const float* W_l2_1 = (const float*)d_in[11];
  const int* edge_index = (const int*)d_in[12];
  float* out = (float*)d_out;

  char* ws = (char*)d_ws;
  float* y    = (float*)ws;                                // 6,400,000 B
  float* agg  = (float*)(ws + 6400000);                    // 15,360,000 B
  int* counts = (int*)(ws + 6400000 + 15360000);           // 80,000 B
  int* cursor = counts + 20000;                            // 80,000 B
  int* eids   = cursor + 20000;                            // 2,560,000 B

  hipMemsetAsync(agg, 0, (size_t)N_NODES*192*sizeof(float), stream);
  hipMemsetAsync(counts, 0, (size_t)N_NODES*sizeof(int), stream);

  k_y   <<<(N_NODES*80+255)/256, 256, 0, stream>>>(node_input, node_attr, W_l1_0, W_l1_1, y);
  k_hist<<<(N_EDGES+255)/256, 256, 0, stream>>>(edge_index, counts);
  k_scan<<<1, 1024, 0, stream>>>(counts, cursor);
  k_fill<<<(N_EDGES+255)/256, 256, 0, stream>>>(edge_index, cursor, eids);
  k_edge<<<512, 256, 0, stream>>>(edge_attr, edge_scalars, W_fc0, W_fc1,
                                  edge_index, eids, y, agg);
  k_finish<<<(N_NODES*80+255)/256, 256, 0, stream>>>(node_input, node_attr, W_sc0, W_sc1,
                                                     W_l2_0, W_l2_1, agg, out);
}

// Round 3
// 381.702 us; speedup vs baseline: 2.5744x; 1.5509x over previous
//
#include <hip/hip_runtime.h>

#define N_NODES 20000
#define N_EDGES 640000
#define N_MT (N_EDGES/16)   // 40000 microtiles of 16 edges

typedef short short8 __attribute__((ext_vector_type(8)));
typedef float f32x4 __attribute__((ext_vector_type(4)));

// RNE float -> bf16 bits
__device__ __forceinline__ unsigned short f2bf(float x){
  unsigned int u = __builtin_bit_cast(unsigned int, x);
  u += 0x7fffu + ((u >> 16) & 1u);
  return (unsigned short)(u >> 16);
}

// wave-synchronous LDS phase boundary: drain LDS ops + stop compiler reordering
__device__ __forceinline__ void wave_lds_fence(){
  __asm__ volatile("s_waitcnt lgkmcnt(0)" ::: "memory");
}

// ---------------- y = per-irrep linear (l1) ----------------
__global__ void k_y(const float* __restrict__ ni, const float* __restrict__ na,
                    const float* __restrict__ Wl10, const float* __restrict__ Wl11,
                    float* __restrict__ y){
  int gid = blockIdx.x*256 + threadIdx.x;
  if (gid >= N_NODES*80) return;
  int n = gid / 80, k = gid - n*80;
  const float* row = ni + (size_t)n*80;
  float a = na[n];
  float acc = 0.f;
  if (k < 32){
    #pragma unroll
    for (int u=0; u<32; ++u) acc += row[u]*Wl10[u*32+k];
    y[gid] = acc * a * 0.17677669529663687f;  // 1/sqrt(32)
  } else {
    int kk = k-32, v = kk/3, i = kk - v*3;
    #pragma unroll
    for (int u=0; u<16; ++u) acc += row[32+u*3+i]*Wl11[u*16+v];
    y[gid] = acc * a * 0.25f;                  // 1/sqrt(16)
  }
}

// ---------------- CSR-ish build (segments contiguous, order arbitrary) -----
__global__ void k_hist(const int* __restrict__ ei, int* __restrict__ counts){
  int e = blockIdx.x*256 + threadIdx.x;
  if (e < N_EDGES) atomicAdd(&counts[ei[N_EDGES + e]], 1);
}

__global__ void k_alloc(const int* __restrict__ counts, int* __restrict__ ctr,
                        int* __restrict__ cursor){
  int n = blockIdx.x*256 + threadIdx.x;
  if (n < N_NODES) cursor[n] = atomicAdd(ctr, counts[n]);
}

__global__ void k_fill(const int* __restrict__ ei, int* __restrict__ cursor,
                       int* __restrict__ eids, int* __restrict__ srcs,
                       int* __restrict__ dsts){
  int e = blockIdx.x*256 + threadIdx.x;
  if (e < N_EDGES){
    int d = ei[N_EDGES + e];
    int pos = atomicAdd(&cursor[d], 1);
    eids[pos] = e;
    srcs[pos] = ei[e];
    dsts[pos] = d;
  }
}

// ---------------- fused edge MLP + messages + segment-sum ----------------
// Per-wave autonomous: each wave owns 16-edge microtiles in a contiguous
// range; NO __syncthreads in the main loop. 3 blocks/CU (LDS ~53 KB).
__global__ __launch_bounds__(256, 3) void k_edge(
    const float* __restrict__ edge_attr, const float* __restrict__ edge_scalars,
    const float* __restrict__ Wfc0, const float* __restrict__ Wfc1,
    const int* __restrict__ eids, const int* __restrict__ srcs,
    const int* __restrict__ dsts,
    const float* __restrict__ y, float* __restrict__ agg){
  __shared__ float s_wfc0[640];          // [k=10][n=64] f32, block-shared
  __shared__ float s_w [4][16*97];       // per-wave: [e=16][o=96(+1)]
  __shared__ float s_y [4][16*80];       // per-wave: gathered y rows
  __shared__ float s_es[4][16*16];       // per-wave: [e=16][k=10, stride16]
  __shared__ float s_ea[4][16*4];        // per-wave: edge_attr rows

  const int t = threadIdx.x;
  const int w = t >> 6, l = t & 63;
  const int r = l & 15, part = l >> 4;

  for (int i = t; i < 640; i += 256) s_wfc0[i] = Wfc0[i];

  // B-fragments of Wfc1 (bf16) live in registers for the whole kernel.
  // Layout for mfma_16x16x32_bf16 B-operand: lane holds B[k=part*8+j][n=nt*16+r].
  short8 b0[6], b1[6];
  #pragma unroll
  for (int nt=0; nt<6; ++nt){
    #pragma unroll
    for (int j=0; j<8; ++j){
      b0[nt][j] = (short)f2bf(Wfc1[(     part*8+j)*96 + nt*16 + r]);
      b1[nt][j] = (short)f2bf(Wfc1[(32 + part*8+j)*96 + nt*16 + r]);
    }
  }
  __syncthreads();   // only barrier: s_wfc0 ready

  // per-lane message-channel constants, 3 passes (c = p*64 + l)
  int o_c[3], yo[3], eai[3];
  bool dot0;
  {
    #pragma unroll
    for (int p=0; p<3; ++p){
      int c = p*64 + l;
      if (c < 32)      { o_c[p]=c;    yo[p]=c;        eai[p]=0; }
      else if (c < 48) { int u=c-32;  o_c[p]=80+u;    yo[p]=32+3*u; eai[p]=0; }
      else if (c < 144){ int idx=c-48;  int u=idx/3, fi=idx-u*3; o_c[p]=32+u; yo[p]=u;        eai[p]=1+fi; }
      else             { int idx=c-144; int u=idx/3, i =idx-u*3; o_c[p]=64+u; yo[p]=32+3*u+i; eai[p]=0; }
    }
    dot0 = (l >= 32) && (l < 48);   // dot channels only exist in pass 0
  }

  float* sw  = s_w[w];
  float* sy  = s_y[w];
  float* ses = s_es[w];
  float* sea = s_ea[w];

  const int gw = blockIdx.x*4 + w;
  const int nw = gridDim.x*4;
  const int m0 = (int)(((long long)gw     * N_MT) / nw);
  const int m1 = (int)(((long long)(gw+1) * N_MT) / nw);

  float acc0 = 0.f, acc1 = 0.f, acc2 = 0.f;
  int dcur = -1;

  for (int m = m0; m < m1; ++m){
    const int base = m*16;
    // coalesced loads of sorted edge meta (each value loaded by 4 lanes)
    const int eid  = eids[base + r];
    const int srcv = srcs[base + r];
    const int dstv = dsts[base + r];

    // ---- stage es/ea (split across parts) + y rows (20 floats/lane)
    {
      const float* esp = edge_scalars + (size_t)eid*10;
      if (part == 0)      *(float4*)(ses + r*16    ) = *(const float4*)(esp);
      else if (part == 1) *(float4*)(ses + r*16 + 4) = *(const float4*)(esp + 4);
      else if (part == 2) *(float2*)(ses + r*16 + 8) = *(const float2*)(esp + 8);
      else                *(float4*)(sea + r*4     ) = *(const float4*)(edge_attr + (size_t)eid*4);
      const float* yp = y + (size_t)srcv*80 + part*20;
      float* syp = sy + r*80 + part*20;
      #pragma unroll
      for (int q=0; q<5; ++q)
        *(float4*)(syp + q*4) = *(const float4*)(yp + q*4);
    }
    wave_lds_fence();

    // ---- layer1 in registers: lane computes h[r][part*8+j] and h[r][32+part*8+j]
    float hv0[8], hv1[8];
    #pragma unroll
    for (int j=0; j<8; ++j){ hv0[j]=0.f; hv1[j]=0.f; }
    {
      const float* esr = ses + r*16;
      #pragma unroll
      for (int k=0; k<10; ++k){
        float ev = esr[k];
        const float* wr = s_wfc0 + k*64 + part*8;
        #pragma unroll
        for (int j=0; j<8; ++j){ hv0[j] += ev*wr[j]; hv1[j] += ev*wr[32+j]; }
      }
    }
    short8 a0, a1;
    #pragma unroll
    for (int j=0; j<8; ++j){
      float x0 = hv0[j]*0.31622776601683794f;   // /sqrt(10)
      float x1 = hv1[j]*0.31622776601683794f;
      a0[j] = (short)f2bf(x0/(1.f+__expf(-x0)));
      a1[j] = (short)f2bf(x1/(1.f+__expf(-x1)));
    }

    // ---- layer2 MFMA: w[e][o], e = part*4+rr, o = nt*16+r
    #pragma unroll
    for (int nt=0; nt<6; ++nt){
      f32x4 acc = {0.f,0.f,0.f,0.f};
      acc = __builtin_amdgcn_mfma_f32_16x16x32_bf16(a0, b0[nt], acc, 0,0,0);
      acc = __builtin_amdgcn_mfma_f32_16x16x32_bf16(a1, b1[nt], acc, 0,0,0);
      #pragma unroll
      for (int rr=0; rr<4; ++rr)
        sw[(part*4+rr)*97 + nt*16 + r] = acc[rr]*0.125f;   // /sqrt(64)
    }
    wave_lds_fence();

    // ---- messages + carried segment-sum (3 channels per lane)
    for (int e=0; e<16; ++e){
      int de = __shfl(dstv, e);
      if (de != dcur){
        if (dcur >= 0){
          unsafeAtomicAdd(&agg[(size_t)dcur*192 +       l], acc0);
          unsafeAtomicAdd(&agg[(size_t)dcur*192 +  64 + l], acc1);
          unsafeAtomicAdd(&agg[(size_t)dcur*192 + 128 + l], acc2);
        }
        acc0 = acc1 = acc2 = 0.f;
        dcur = de;
      }
      const float* swe  = sw  + e*97;
      const float* sye  = sy  + e*80;
      const float* seae = sea + e*4;
      float m0v;
      if (dot0){
        m0v = swe[o_c[0]] * (sye[yo[0]]*seae[1] + sye[yo[0]+1]*seae[2] + sye[yo[0]+2]*seae[3])
              * 0.5773502691896258f;   // /sqrt(3)
      } else {
        m0v = swe[o_c[0]] * sye[yo[0]] * seae[eai[0]];
      }
      acc0 += m0v;
      acc1 += swe[o_c[1]] * sye[yo[1]] * seae[eai[1]];
      acc2 += swe[o_c[2]] * sye[yo[2]] * seae[eai[2]];
    }
    wave_lds_fence();
  }
  if (dcur >= 0){
    unsafeAtomicAdd(&agg[(size_t)dcur*192 +       l], acc0);
    unsafeAtomicAdd(&agg[(size_t)dcur*192 +  64 + l], acc1);
    unsafeAtomicAdd(&agg[(size_t)dcur*192 + 128 + l], acc2);
  }
}

// ---------------- finish: z = agg @ W_l2, out = c_s*s + c_x*z ----------------
__global__ void k_finish(const float* __restrict__ ni, const float* __restrict__ na,
    const float* __restrict__ Wsc0, const float* __restrict__ Wsc1,
    const float* __restrict__ Wl20, const float* __restrict__ Wl21,
    const float* __restrict__ agg, float* __restrict__ out){
  int gid = blockIdx.x*256 + threadIdx.x;
  if (gid >= N_NODES*80) return;
  int n = gid / 80, k = gid - n*80;
  const float* row = ni + (size_t)n*80;
  const float* ag  = agg + (size_t)n*192;
  float a = na[n];
  const float c_s = 0.3826834323650898f;   // sin(pi/8)
  const float c_x = 0.9238795325112867f;   // cos(pi/8)
  const float zscale = 0.17677669529663687f * 0.14433756729740643f; // 1/sqrt(32)/sqrt(48)
  float s = 0.f, z = 0.f;
  if (k < 32){
    #pragma unroll
    for (int u=0; u<32; ++u) s += row[u]*Wsc0[u*32+k];
    s *= a * 0.17677669529663687f;
    #pragma unroll
    for (int u=0; u<48; ++u) z += ag[u]*Wl20[u*32+k];
  } else {
    int kk=k-32, v=kk/3, i=kk-v*3;
    #pragma unroll
    for (int u=0; u<16; ++u) s += row[32+u*3+i]*Wsc1[u*16+v];
    s *= a * 0.25f;
    #pragma unroll
    for (int u=0; u<48; ++u) z += ag[48+u*3+i]*Wl21[u*16+v];
  }
  out[gid] = c_s*s + c_x*z*zscale;
}

extern "C" void kernel_launch(void* const* d_in, const int* in_sizes, int n_in,
                              void* d_out, int out_size, void* d_ws, size_t ws_size,
                              hipStream_t stream){
  const float* node_input   = (const float*)d_in[0];
  const float* node_attr    = (const float*)d_in[1];
  const float* edge_attr    = (const float*)d_in[2];
  const float* edge_scalars = (const float*)d_in[3];
  const float* W_sc0 = (const float*)d_in[4];
  const float* W_sc1 = (const float*)d_in[5];
  const float* W_l1_0 = (const float*)d_in[6];
  const float* W_l1_1 = (const float*)d_in[7];
  const float* W_fc0 = (const float*)d_in[8];
  const float* W_fc1 = (const float*)d_in[9];
  const float* W_l2_0 = (const float*)d_in[10];
  const float* W_l2_1 = (const float*)d_in[11];
  const int* edge_index = (const int*)d_in[12];
  float* out = (float*)d_out;

  char* ws = (char*)d_ws;
  float* y    = (float*)ws;                                // 6,400,000 B
  float* agg  = (float*)(ws + 6400000);                    // 15,360,000 B
  int* counts = (int*)(ws + 6400000 + 15360000);           // 20000 ints
  int* ctr    = counts + 20000;                            // 1 int (+pad)
  int* cursor = counts + 20008;                            // 20000 ints
  int* eids   = cursor + 20000;                            // 640000 ints
  int* srcs   = eids + N_EDGES;                            // 640000 ints
  int* dsts   = srcs + N_EDGES;                            // 640000 ints

  hipMemsetAsync(agg, 0, (size_t)N_NODES*192*sizeof(float), stream);
  hipMemsetAsync(counts, 0, (size_t)(20008)*sizeof(int), stream);  // counts + ctr

  k_hist <<<(N_EDGES+255)/256, 256, 0, stream>>>(edge_index, counts);
  k_alloc<<<(N_NODES+255)/256, 256, 0, stream>>>(counts, ctr, cursor);
  k_fill <<<(N_EDGES+255)/256, 256, 0, stream>>>(edge_index, cursor, eids, srcs, dsts);
  k_y    <<<(N_NODES*80+255)/256, 256, 0, stream>>>(node_input, node_attr, W_l1_0, W_l1_1, y);
  k_edge <<<768, 256, 0, stream>>>(edge_attr, edge_scalars, W_fc0, W_fc1,
                                   eids, srcs, dsts, y, agg);
  k_finish<<<(N_NODES*80+255)/256, 256, 0, stream>>>(node_input, node_attr, W_sc0, W_sc1,
                                                     W_l2_0, W_l2_1, agg, out);
}